// Round 8
// baseline (288.687 us; speedup 1.0000x reference)
//
#include <hip/hip_runtime.h>

// RelativeSAMAttention: B=4,H=8,N=1024,DH=128. Outputs FP32: out[B,H,N,DH] ++ scores[B,H,N,N].
//
// R11: R8 (88.4us best) with ONE change: replay reads V fragments DIRECT from L2-hot wsVt
// (no V LDS staging) -> replay loop has zero vmem the barrier must drain, so the sP-dbuf
// barrier becomes lgkmcnt-only (inline asm s_barrier). NT score stores float across all
// 15 replay barriers (previously each __syncthreads drained vmcnt(0): V-stage + NT-store
// ack ~300-900cy x15). V loads are compiler-tracked (waitcnt before MFMA) and hidden by
// 16+ resident waves; bh-major block order keeps the 256KB V^T set L2-resident.
//   - pass1: R8 verbatim (64-col tile gl_lds dbuf, 16 full-drain barriers — needed there).
//   - launch_bounds(512,4): R6/R7b lesson — tighter caps spill the 32-VGPR score cache.
//   - LDS ~40.6KB (pass1 K dbuf 32KB + sP dbuf 8KB + red).

typedef __attribute__((ext_vector_type(8))) short short8;
typedef __attribute__((ext_vector_type(4))) float f32x4;

#define OUT_ELEMS 4194304ull
#define WS_K      0ull           //  8388608 B bf16 K [bh][m][dh]
#define WS_VT     8388608ull     //  8388608 B bf16 V^T [bh][dh][m]
#define WS_CS     16777216ull    //      128 B fp32 cs[32]

__device__ __forceinline__ unsigned short f2bf(float f) {
    unsigned u = __builtin_bit_cast(unsigned, f);
    u += 0x7FFFu + ((u >> 16) & 1u);
    return (unsigned short)(u >> 16);
}
__device__ __forceinline__ float bf2f(unsigned short u) {
    return __builtin_bit_cast(float, (unsigned)u << 16);
}
__device__ __forceinline__ float softplus(float x) {
    return fmaxf(x, 0.f) + __logf(1.f + __expf(-fabsf(x)));
}
__device__ __forceinline__ unsigned cvt_pk_bf16(float lo, float hi) {
    unsigned r;
    asm("v_cvt_pk_bf16_f32 %0, %1, %2" : "=v"(r) : "v"(lo), "v"(hi));
    return r;
}
__device__ __forceinline__ void gl_lds16(const unsigned short* g, unsigned short* l) {
    __builtin_amdgcn_global_load_lds(
        (const __attribute__((address_space(1))) void*)g,
        (__attribute__((address_space(3))) void*)l, 16, 0, 0);
}

// ---------------- merged prep: blocks [0,512) K-convert, [512,1024) V-transpose, [1024,1056) cs ----
__global__ __launch_bounds__(256) void prep_all(
    const float* __restrict__ k, const float* __restrict__ v, const float* __restrict__ c,
    unsigned short* __restrict__ wsK, unsigned short* __restrict__ wsVt, float* __restrict__ wsCs)
{
    __shared__ unsigned short sT[64 * 132];
    const int blk = blockIdx.x, tid = threadIdx.x;
    if (blk < 512) {
        int t = blk * 256 + tid;
        for (int u = t; u < 524288; u += 131072) {
            float4 a = reinterpret_cast<const float4*>(k)[u * 2];
            float4 b = reinterpret_cast<const float4*>(k)[u * 2 + 1];
            short8 o;
            o[0]=(short)f2bf(a.x); o[1]=(short)f2bf(a.y); o[2]=(short)f2bf(a.z); o[3]=(short)f2bf(a.w);
            o[4]=(short)f2bf(b.x); o[5]=(short)f2bf(b.y); o[6]=(short)f2bf(b.z); o[7]=(short)f2bf(b.w);
            reinterpret_cast<short8*>(wsK)[u] = o;
        }
    } else if (blk < 1024) {
        const int vb = blk - 512;
        const int bh = vb >> 4, m0 = (vb & 15) * 64;
        const float* src = v + ((size_t)bh * 1024 + m0) * 128;
        for (int i = tid; i < 2048; i += 256) {
            int row = i >> 5, c4 = i & 31;
            float4 t = reinterpret_cast<const float4*>(src)[i];
            unsigned long long pk = (unsigned long long)f2bf(t.x)
                                  | ((unsigned long long)f2bf(t.y) << 16)
                                  | ((unsigned long long)f2bf(t.z) << 32)
                                  | ((unsigned long long)f2bf(t.w) << 48);
            *reinterpret_cast<unsigned long long*>(&sT[row * 132 + c4 * 4]) = pk;
        }
        __syncthreads();
        for (int u = tid; u < 2048; u += 256) {
            int dh = u >> 4, ms = u & 15;
            unsigned long long pk = (unsigned long long)sT[(ms*4+0)*132 + dh]
                                  | ((unsigned long long)sT[(ms*4+1)*132 + dh] << 16)
                                  | ((unsigned long long)sT[(ms*4+2)*132 + dh] << 32)
                                  | ((unsigned long long)sT[(ms*4+3)*132 + dh] << 48);
            *reinterpret_cast<unsigned long long*>(&wsVt[((size_t)bh * 128 + dh) * 1024 + m0 + ms * 4]) = pk;
        }
    } else {
        __shared__ float red[4];
        const int bh = blk - 1024;
        float p = 0.f;
        for (int i = tid; i < 1024; i += 256) p += softplus(c[(size_t)bh * 1024 + i]);
        p += __shfl_xor(p, 32, 64); p += __shfl_xor(p, 16, 64); p += __shfl_xor(p, 8, 64);
        p += __shfl_xor(p,  4, 64); p += __shfl_xor(p,  2, 64); p += __shfl_xor(p, 1, 64);
        if ((tid & 63) == 0) red[tid >> 6] = p;
        __syncthreads();
        if (tid == 0) wsCs[bh] = red[0] + red[1] + red[2] + red[3] + 1e-9f;
    }
}

// ---------------- main: R8 pass1 + V-direct replay with lgkm-only barriers ----------------
__global__ __launch_bounds__(512, 4) void sam_main(
    const float* __restrict__ q, const float* __restrict__ dqp, const float* __restrict__ dkp,
    const float* __restrict__ w_w, const float* __restrict__ b_w,
    const float* __restrict__ w_b, const float* __restrict__ b_b,
    const unsigned short* __restrict__ wsK, const unsigned short* __restrict__ wsVt,
    const float* __restrict__ wsCs, float* __restrict__ out)
{
    __shared__ __align__(16) unsigned short uSh[16384];  // 32KB: pass1 K dbuf [2][64][128]; sQ[32][136]
    __shared__ __align__(16) unsigned short sPb[4096];   //  8KB: sP[2][32][64], granule-XOR swizzled
    __shared__ float s_red[128];
    __shared__ float s_inv[32];

    const int bid  = blockIdx.x;
    const int xcd  = bid & 7;                 // round-robin XCD assumption (perf-only)
    const int j    = bid >> 3;                // 0..127 within XCD
    const int bh   = xcd * 4 + (j >> 5);      // bh-MAJOR: concurrent blocks share one bh (512KB, L2-hot)
    const int n0   = (j & 31) * 32;
    const int b    = bh >> 3;
    const int h    = bh & 7;
    const int tid  = threadIdx.x;
    const int lane = tid & 63;
    const int wave = tid >> 6;
    const int l15  = lane & 15;
    const int quad = lane >> 4;
    const int wr   = wave >> 2;               // row half (16 rows)
    const int wc   = wave & 3;                // col quarter (16 m) / dh quarter (32 dh)
    const int mq   = wc * 16 + l15;
    const int swz3 = l15 & 7;
    const int r0   = wr * 16 + quad * 4;
    const int q4   = (quad & 1) * 4;          // (r0+r)&7 = q4+r (no carry, r<4)

    const float ww = w_w[h], bw = b_w[h], wb = w_b[h], bb = b_b[h];
    const float wwn = -ww, bwn = -bw;
    const float SCALE = 0.08838834764831845f;   // 1/sqrt(128), folded into Q

    // ---- staging geometry ----
    const unsigned short* gKbh = wsK  + (size_t)bh * 131072;
    const unsigned short* gVbh = wsVt + (size_t)bh * 131072;
    const int krow  = tid >> 4;                                 // K-stage row (i=0): 0..31
    const int koff0 = krow * 128 + (((tid & 15) ^ (krow & 7)) << 3);
    const int ldsoW = wave * 512;                               // wave-uniform dest (shorts)

    auto stageK = [&](int buf, int t) {
        const unsigned short* g = gKbh + t * 8192 + koff0;
        gl_lds16(g,        &uSh[buf * 8192 + ldsoW]);
        gl_lds16(g + 4096, &uSh[buf * 8192 + 4096 + ldsoW]);    // row+32: same low3 bits
    };

    // ---- prologue: prefetch K tile 0 into buf1; Q rows -> bf16 (pre-scaled) sQ (buf0) ----
    stageK(1, 0);
    {
        const float* qbase = q + ((size_t)bh * 1024 + n0) * 128;
        for (int i = tid; i < 1024; i += 512) {
            int row = i >> 5, c4 = i & 31;
            float4 t = reinterpret_cast<const float4*>(qbase)[i];
            unsigned long long pk = (unsigned long long)f2bf(t.x * SCALE)
                                  | ((unsigned long long)f2bf(t.y * SCALE) << 16)
                                  | ((unsigned long long)f2bf(t.z * SCALE) << 32)
                                  | ((unsigned long long)f2bf(t.w * SCALE) << 48);
            *reinterpret_cast<unsigned long long*>(&uSh[row * 136 + c4 * 4]) = pk;
        }
    }
    float qxm[4], qym[4], qzm[4], qs[4];
    #pragma unroll
    for (int r = 0; r < 4; r++) {
        float4 d4 = reinterpret_cast<const float4*>(dqp)[(size_t)b * 1024 + n0 + r0 + r];
        qxm[r] = -2.f * d4.x; qym[r] = -2.f * d4.y; qzm[r] = -2.f * d4.z;
        qs[r] = d4.x*d4.x + d4.y*d4.y + d4.z*d4.z;
    }
    const float cs = wsCs[bh];
    __syncthreads();                           // sQ visible; stageK(1,0) drained
    short8 afr[4];
    {
        const unsigned short* aq = &uSh[(wr * 16 + l15) * 136 + quad * 8];
        #pragma unroll
        for (int ks = 0; ks < 4; ks++)
            afr[ks] = *reinterpret_cast<const short8*>(aq + ks * 32);
    }
    __syncthreads();                           // all afr reads done; buf0 free

    const float4* dkb = reinterpret_cast<const float4*>(dkp) + (size_t)b * 1024 + mq;

    // ================= PASS 1 (R8 verbatim): 1 full barrier/tile, staging overlapped =================
    float rs[4] = {0.f, 0.f, 0.f, 0.f};
    unsigned vreg[16][2];                      // raw-score cache: 16 tiles x 4 vals packed bf16
    #pragma unroll
    for (int t = 0; t < 16; t++) {
        const int bswz = (1 ^ (t & 1)) * 8192; // read buf: t0->1, t1->0, ...
        if (t < 15) stageK(t & 1, t + 1);      // async prefetch next tile
        f32x4 cacc = {0.f, 0.f, 0.f, 0.f};
        const unsigned short* bq = &uSh[bswz + mq * 128];
        #pragma unroll
        for (int ks = 0; ks < 4; ks++) {
            short8 bfr = *reinterpret_cast<const short8*>(bq + (((ks * 4 + quad) ^ swz3) << 3));
            cacc = __builtin_amdgcn_mfma_f32_16x16x32_bf16(afr[ks], bfr, cacc, 0, 0, 0);
        }
        float4 d4 = dkb[t * 64];
        float ksq = d4.x*d4.x + d4.y*d4.y + d4.z*d4.z;
        float val[4];
        #pragma unroll
        for (int r = 0; r < 4; r++) {
            float dist = qs[r] + ksq + qxm[r]*d4.x + qym[r]*d4.y + qzm[r]*d4.z;
            float aw = softplus(dist * wwn + bwn);
            float ab = dist * wb + bb;
            val[r] = fmaxf(cacc[r] * aw + ab, 0.f);
            rs[r] += val[r];
        }
        vreg[t][0] = cvt_pk_bf16(val[0], val[1]);
        vreg[t][1] = cvt_pk_bf16(val[2], val[3]);
        __syncthreads();                       // cur-buf reads done + next stage landed
    }

    // ---- transition (R8 minus stageV): rowsums -> invd; preload sP[0] ----
    #pragma unroll
    for (int r = 0; r < 4; r++) {
        float ts = rs[r];
        ts += __shfl_xor(ts, 1, 64);
        ts += __shfl_xor(ts, 2, 64);
        ts += __shfl_xor(ts, 4, 64);
        ts += __shfl_xor(ts, 8, 64);
        if (l15 == 0) s_red[wc * 32 + r0 + r] = ts;
    }
    auto sp_write = [&](int buf, unsigned pv0, unsigned pv1) {
        unsigned short* pb = sPb + buf * 2048;
        const int gm = mq >> 3, c7 = mq & 7;
        pb[(r0 + 0) * 64 + (((gm ^ (q4 + 0)) << 3) | c7)] = (unsigned short)(pv0);
        pb[(r0 + 1) * 64 + (((gm ^ (q4 + 1)) << 3) | c7)] = (unsigned short)(pv0 >> 16);
        pb[(r0 + 2) * 64 + (((gm ^ (q4 + 2)) << 3) | c7)] = (unsigned short)(pv1);
        pb[(r0 + 3) * 64 + (((gm ^ (q4 + 3)) << 3) | c7)] = (unsigned short)(pv1 >> 16);
    };
    sp_write(0, vreg[0][0], vreg[0][1]);
    __syncthreads();
    if (tid < 32) s_inv[tid] = 1.f / (s_red[tid] + s_red[32 + tid] + s_red[64 + tid] + s_red[96 + tid] + cs);
    __syncthreads();

    float inv4[4];
    #pragma unroll
    for (int r = 0; r < 4; r++) inv4[r] = s_inv[r0 + r];

    // ================= REPLAY: V direct from L2; lgkm-only barrier (NT stores float) =================
    f32x4 oacc[2];
    oacc[0] = {0.f, 0.f, 0.f, 0.f};
    oacc[1] = {0.f, 0.f, 0.f, 0.f};
    const int crow = tid >> 4, cc4 = tid & 15;             // cooperative-store coords
    const int cidx = crow * 64 + ((((cc4 >> 1) ^ (crow & 7)) << 3) | ((cc4 & 1) << 2));
    float* scrow = out + OUT_ELEMS + ((size_t)bh << 20) + (size_t)(n0 + crow) * 1024 + cc4 * 4;
    const float cinv = s_inv[crow];
    const int prow = wr * 16 + l15;
    // V fragment bases: dh = wc*32 + df*16 + l15; per-tile/ks2 offsets are compile-time imm
    const unsigned short* vb0 = gVbh + (size_t)(wc * 32 + l15) * 1024 + quad * 8;
    const unsigned short* vb1 = vb0 + 16 * 1024;

    #pragma unroll
    for (int t = 0; t < 16; t++) {
        const int bb2 = t & 1;
        if (t < 15) sp_write(bb2 ^ 1, vreg[t + 1][0], vreg[t + 1][1]);
        {   // cooperative coalesced score store: full 128B lines, nontemporal (never drained in-loop)
            unsigned long long pk = *reinterpret_cast<const unsigned long long*>(&sPb[bb2 * 2048 + cidx]);
            f32x4 o;
            o[0] = bf2f((unsigned short)(pk      )) * cinv;
            o[1] = bf2f((unsigned short)(pk >> 16)) * cinv;
            o[2] = bf2f((unsigned short)(pk >> 32)) * cinv;
            o[3] = bf2f((unsigned short)(pk >> 48)) * cinv;
            __builtin_nontemporal_store(o, reinterpret_cast<f32x4*>(scrow + t * 64));
        }
        #pragma unroll
        for (int ks2 = 0; ks2 < 2; ks2++) {
            short8 pfr = *reinterpret_cast<const short8*>(
                &sPb[bb2 * 2048 + prow * 64 + (((ks2 * 4 + quad) ^ swz3) << 3)]);
            short8 vfr0 = *reinterpret_cast<const short8*>(vb0 + t * 64 + ks2 * 32);
            short8 vfr1 = *reinterpret_cast<const short8*>(vb1 + t * 64 + ks2 * 32);
            oacc[0] = __builtin_amdgcn_mfma_f32_16x16x32_bf16(pfr, vfr0, oacc[0], 0, 0, 0);
            oacc[1] = __builtin_amdgcn_mfma_f32_16x16x32_bf16(pfr, vfr1, oacc[1], 0, 0, 0);
        }
        if (t < 15)
            asm volatile("s_waitcnt lgkmcnt(0)\n\ts_barrier" ::: "memory");
    }

    // ---- epilogue (R8 verbatim): O = inv[row] * acc (waves own disjoint (row,dh)) ----
    {
        float* obase = out + ((size_t)bh * 1024 + n0 + r0) * 128 + wc * 32 + l15;
        #pragma unroll
        for (int df = 0; df < 2; df++)
            #pragma unroll
            for (int r = 0; r < 4; r++)
                obase[(size_t)r * 128 + df * 16] = oacc[df][r] * inv4[r];
    }
}

extern "C" void kernel_launch(void* const* d_in, const int* in_sizes, int n_in,
                              void* d_out, int out_size, void* d_ws, size_t ws_size,
                              hipStream_t stream) {
    const float* q   = (const float*)d_in[0];
    const float* k   = (const float*)d_in[1];
    const float* v   = (const float*)d_in[2];
    const float* c   = (const float*)d_in[3];
    const float* dq  = (const float*)d_in[4];
    const float* dk  = (const float*)d_in[5];
    const float* w_w = (const float*)d_in[6];
    const float* b_w = (const float*)d_in[7];
    const float* w_b = (const float*)d_in[8];
    const float* b_b = (const float*)d_in[9];
    float* out = (float*)d_out;
    char* ws = (char*)d_ws;
    unsigned short* wsK  = (unsigned short*)(ws + WS_K);
    unsigned short* wsVt = (unsigned short*)(ws + WS_VT);
    float* wsCs   = (float*)(ws + WS_CS);

    hipLaunchKernelGGL(prep_all, dim3(1056), dim3(256), 0, stream, k, v, c, wsK, wsVt, wsCs);
    hipLaunchKernelGGL(sam_main, dim3(1024), dim3(512), 0, stream,
                       q, dq, dk, w_w, b_w, w_b, b_b, wsK, wsVt, wsCs, out);
}

// Round 9
// 266.971 us; speedup vs baseline: 1.0813x; 1.0813x over previous
//
#include <hip/hip_runtime.h>

// RelativeSAMAttention: B=4,H=8,N=1024,DH=128. Outputs FP32: out[B,H,N,DH] ++ scores[B,H,N,N].
//
// R12: R8 (88.4us, verified best) at HALF block granularity for 2x barrier domains/CU.
//   R8 evidence: VALU~31us, HBM~30us, MFMA~6.5us all overlappable, yet 88us -> ~50us of
//   barrier/drain dead time across 31 block-wide barriers at 2 blocks/CU. R11 killed the
//   V-direct alternative (twice refuted). So: 16-row blocks, 256 thr (4 waves), 2048 blocks,
//   launch_bounds(256,4) -> 4 blocks/CU (LDS 36.6KB, reg cap 128 unchanged -> no spill).
//   One block's barrier stall now hides under 3 other blocks' compute.
//   All R8 mechanics verbatim (indices scaled): async gl_lds dbuf staging + XOR-swizzled
//   source, 1 barrier/tile, sP dbuf replay, full-128B-line NT score stores, bh-major order.
//   Cost: K/V staged by 2x blocks -> 2x L2 re-reads (L2-hot, overlapped).

typedef __attribute__((ext_vector_type(8))) short short8;
typedef __attribute__((ext_vector_type(4))) float f32x4;

#define OUT_ELEMS 4194304ull
#define WS_K      0ull           //  8388608 B bf16 K [bh][m][dh]
#define WS_VT     8388608ull     //  8388608 B bf16 V^T [bh][dh][m]
#define WS_CS     16777216ull    //      128 B fp32 cs[32]

__device__ __forceinline__ unsigned short f2bf(float f) {
    unsigned u = __builtin_bit_cast(unsigned, f);
    u += 0x7FFFu + ((u >> 16) & 1u);
    return (unsigned short)(u >> 16);
}
__device__ __forceinline__ float bf2f(unsigned short u) {
    return __builtin_bit_cast(float, (unsigned)u << 16);
}
__device__ __forceinline__ float softplus(float x) {
    return fmaxf(x, 0.f) + __logf(1.f + __expf(-fabsf(x)));
}
__device__ __forceinline__ unsigned cvt_pk_bf16(float lo, float hi) {
    unsigned r;
    asm("v_cvt_pk_bf16_f32 %0, %1, %2" : "=v"(r) : "v"(lo), "v"(hi));
    return r;
}
__device__ __forceinline__ void gl_lds16(const unsigned short* g, unsigned short* l) {
    __builtin_amdgcn_global_load_lds(
        (const __attribute__((address_space(1))) void*)g,
        (__attribute__((address_space(3))) void*)l, 16, 0, 0);
}

// ---------------- merged prep: blocks [0,512) K-convert, [512,1024) V-transpose, [1024,1056) cs ----
__global__ __launch_bounds__(256) void prep_all(
    const float* __restrict__ k, const float* __restrict__ v, const float* __restrict__ c,
    unsigned short* __restrict__ wsK, unsigned short* __restrict__ wsVt, float* __restrict__ wsCs)
{
    __shared__ unsigned short sT[64 * 132];
    const int blk = blockIdx.x, tid = threadIdx.x;
    if (blk < 512) {
        int t = blk * 256 + tid;
        for (int u = t; u < 524288; u += 131072) {
            float4 a = reinterpret_cast<const float4*>(k)[u * 2];
            float4 b = reinterpret_cast<const float4*>(k)[u * 2 + 1];
            short8 o;
            o[0]=(short)f2bf(a.x); o[1]=(short)f2bf(a.y); o[2]=(short)f2bf(a.z); o[3]=(short)f2bf(a.w);
            o[4]=(short)f2bf(b.x); o[5]=(short)f2bf(b.y); o[6]=(short)f2bf(b.z); o[7]=(short)f2bf(b.w);
            reinterpret_cast<short8*>(wsK)[u] = o;
        }
    } else if (blk < 1024) {
        const int vb = blk - 512;
        const int bh = vb >> 4, m0 = (vb & 15) * 64;
        const float* src = v + ((size_t)bh * 1024 + m0) * 128;
        for (int i = tid; i < 2048; i += 256) {
            int row = i >> 5, c4 = i & 31;
            float4 t = reinterpret_cast<const float4*>(src)[i];
            unsigned long long pk = (unsigned long long)f2bf(t.x)
                                  | ((unsigned long long)f2bf(t.y) << 16)
                                  | ((unsigned long long)f2bf(t.z) << 32)
                                  | ((unsigned long long)f2bf(t.w) << 48);
            *reinterpret_cast<unsigned long long*>(&sT[row * 132 + c4 * 4]) = pk;
        }
        __syncthreads();
        for (int u = tid; u < 2048; u += 256) {
            int dh = u >> 4, ms = u & 15;
            unsigned long long pk = (unsigned long long)sT[(ms*4+0)*132 + dh]
                                  | ((unsigned long long)sT[(ms*4+1)*132 + dh] << 16)
                                  | ((unsigned long long)sT[(ms*4+2)*132 + dh] << 32)
                                  | ((unsigned long long)sT[(ms*4+3)*132 + dh] << 48);
            *reinterpret_cast<unsigned long long*>(&wsVt[((size_t)bh * 128 + dh) * 1024 + m0 + ms * 4]) = pk;
        }
    } else {
        __shared__ float red[4];
        const int bh = blk - 1024;
        float p = 0.f;
        for (int i = tid; i < 1024; i += 256) p += softplus(c[(size_t)bh * 1024 + i]);
        p += __shfl_xor(p, 32, 64); p += __shfl_xor(p, 16, 64); p += __shfl_xor(p, 8, 64);
        p += __shfl_xor(p,  4, 64); p += __shfl_xor(p,  2, 64); p += __shfl_xor(p, 1, 64);
        if ((tid & 63) == 0) red[tid >> 6] = p;
        __syncthreads();
        if (tid == 0) wsCs[bh] = red[0] + red[1] + red[2] + red[3] + 1e-9f;
    }
}

// ---------------- main: 16-row blocks, 4 blocks/CU, R8 mechanics ----------------
__global__ __launch_bounds__(256, 4) void sam_main(
    const float* __restrict__ q, const float* __restrict__ dqp, const float* __restrict__ dkp,
    const float* __restrict__ w_w, const float* __restrict__ b_w,
    const float* __restrict__ w_b, const float* __restrict__ b_b,
    const unsigned short* __restrict__ wsK, const unsigned short* __restrict__ wsVt,
    const float* __restrict__ wsCs, float* __restrict__ out)
{
    __shared__ __align__(16) unsigned short uSh[16384];  // 32KB: K dbuf [2][64][128] / V dbuf [2][128][64]; sQ[16][136]
    __shared__ __align__(16) unsigned short sPb[2048];   //  4KB: sP[2][16][64], granule-XOR swizzled
    __shared__ float s_red[64];
    __shared__ float s_inv[16];

    const int bid  = blockIdx.x;
    const int xcd  = bid & 7;                 // round-robin XCD assumption (perf-only)
    const int j    = bid >> 3;                // 0..255 within XCD
    const int bh   = xcd * 4 + (j >> 6);      // bh-MAJOR: concurrent blocks share one bh (512KB, L2-hot)
    const int n0   = (j & 63) * 16;
    const int b    = bh >> 3;
    const int h    = bh & 7;
    const int tid  = threadIdx.x;
    const int lane = tid & 63;
    const int wave = tid >> 6;                // 0..3
    const int l15  = lane & 15;
    const int quad = lane >> 4;
    const int wc   = wave;                    // col quarter (16 m) / dh quarter (32 dh)
    const int mq   = wc * 16 + l15;
    const int swz3 = l15 & 7;
    const int r0   = quad * 4;                // block-local row base (16 rows total)
    const int q4   = (quad & 1) * 4;          // (r0+r)&7 = q4+r (no carry, r<4)

    const float ww = w_w[h], bw = b_w[h], wb = w_b[h], bb = b_b[h];
    const float wwn = -ww, bwn = -bw;
    const float SCALE = 0.08838834764831845f;   // 1/sqrt(128), folded into Q

    // ---- staging geometry ----
    const unsigned short* gKbh = wsK  + (size_t)bh * 131072;
    const unsigned short* gVbh = wsVt + (size_t)bh * 131072;
    const int krow  = tid >> 4;                                 // K-stage row (i=0): 0..15
    const int koff0 = krow * 128 + (((tid & 15) ^ (krow & 7)) << 3);
    const int vdh   = tid >> 3;                                 // V-stage dh (i=0): 0..31
    const int voff0 = vdh * 1024 + (((tid & 7) ^ (vdh & 7)) << 3);
    const int ldsoW = wave * 512;                               // wave-uniform dest (shorts)

    auto stageK = [&](int buf, int t) {                         // K tile t: 64 rows x 128 dh
        const unsigned short* g = gKbh + t * 8192 + koff0;
        #pragma unroll
        for (int i = 0; i < 4; i++)                             // rows +16 each: (row&7) invariant
            gl_lds16(g + i * 2048, &uSh[buf * 8192 + i * 2048 + ldsoW]);
    };
    auto stageV = [&](int buf, int t) {                         // V tile t: 128 dh x 64 m
        const unsigned short* g = gVbh + t * 64 + voff0;
        #pragma unroll
        for (int i = 0; i < 4; i++)                             // dh +32 each: (dh&7) invariant
            gl_lds16(g + i * 32768, &uSh[buf * 8192 + i * 2048 + ldsoW]);
    };

    // ---- prologue: prefetch K tile 0 into buf1; Q rows [n0,n0+16) -> bf16 (pre-scaled) sQ (buf0) ----
    stageK(1, 0);
    {
        const float* qbase = q + ((size_t)bh * 1024 + n0) * 128;
        for (int i = tid; i < 512; i += 256) {
            int row = i >> 5, c4 = i & 31;
            float4 t = reinterpret_cast<const float4*>(qbase)[i];
            unsigned long long pk = (unsigned long long)f2bf(t.x * SCALE)
                                  | ((unsigned long long)f2bf(t.y * SCALE) << 16)
                                  | ((unsigned long long)f2bf(t.z * SCALE) << 32)
                                  | ((unsigned long long)f2bf(t.w * SCALE) << 48);
            *reinterpret_cast<unsigned long long*>(&uSh[row * 136 + c4 * 4]) = pk;
        }
    }
    float qxm[4], qym[4], qzm[4], qs[4];
    #pragma unroll
    for (int r = 0; r < 4; r++) {
        float4 d4 = reinterpret_cast<const float4*>(dqp)[(size_t)b * 1024 + n0 + r0 + r];
        qxm[r] = -2.f * d4.x; qym[r] = -2.f * d4.y; qzm[r] = -2.f * d4.z;
        qs[r] = d4.x*d4.x + d4.y*d4.y + d4.z*d4.z;
    }
    const float cs = wsCs[bh];
    __syncthreads();                           // sQ visible; stageK(1,0) drained
    short8 afr[4];
    {
        const unsigned short* aq = &uSh[l15 * 136 + quad * 8];
        #pragma unroll
        for (int ks = 0; ks < 4; ks++)
            afr[ks] = *reinterpret_cast<const short8*>(aq + ks * 32);
    }
    __syncthreads();                           // all afr reads done; buf0 free

    const float4* dkb = reinterpret_cast<const float4*>(dkp) + (size_t)b * 1024 + mq;

    // ================= PASS 1: 1 barrier/tile, staging overlapped =================
    float rs[4] = {0.f, 0.f, 0.f, 0.f};
    unsigned vreg[16][2];                      // raw-score cache: 16 tiles x 4 vals packed bf16
    #pragma unroll
    for (int t = 0; t < 16; t++) {
        const int bswz = (1 ^ (t & 1)) * 8192; // read buf: t0->1, t1->0, ...
        if (t < 15) stageK(t & 1, t + 1);      // async prefetch next tile
        f32x4 cacc = {0.f, 0.f, 0.f, 0.f};
        const unsigned short* bq = &uSh[bswz + mq * 128];
        #pragma unroll
        for (int ks = 0; ks < 4; ks++) {
            short8 bfr = *reinterpret_cast<const short8*>(bq + (((ks * 4 + quad) ^ swz3) << 3));
            cacc = __builtin_amdgcn_mfma_f32_16x16x32_bf16(afr[ks], bfr, cacc, 0, 0, 0);
        }
        float4 d4 = dkb[t * 64];
        float ksq = d4.x*d4.x + d4.y*d4.y + d4.z*d4.z;
        float val[4];
        #pragma unroll
        for (int r = 0; r < 4; r++) {
            float dist = qs[r] + ksq + qxm[r]*d4.x + qym[r]*d4.y + qzm[r]*d4.z;
            float aw = softplus(dist * wwn + bwn);
            float ab = dist * wb + bb;
            val[r] = fmaxf(cacc[r] * aw + ab, 0.f);
            rs[r] += val[r];
        }
        vreg[t][0] = cvt_pk_bf16(val[0], val[1]);
        vreg[t][1] = cvt_pk_bf16(val[2], val[3]);
        __syncthreads();                       // cur-buf reads done + next stage landed
    }

    // ---- transition: rowsums -> invd; prefetch V tile 0 (buf0) + sP[0] ----
    #pragma unroll
    for (int r = 0; r < 4; r++) {
        float ts = rs[r];
        ts += __shfl_xor(ts, 1, 64);
        ts += __shfl_xor(ts, 2, 64);
        ts += __shfl_xor(ts, 4, 64);
        ts += __shfl_xor(ts, 8, 64);
        if (l15 == 0) s_red[wc * 16 + r0 + r] = ts;
    }
    auto sp_write = [&](int buf, unsigned pv0, unsigned pv1) {
        unsigned short* pb = sPb + buf * 1024;
        const int gm = mq >> 3, c7 = mq & 7;
        pb[(r0 + 0) * 64 + (((gm ^ (q4 + 0)) << 3) | c7)] = (unsigned short)(pv0);
        pb[(r0 + 1) * 64 + (((gm ^ (q4 + 1)) << 3) | c7)] = (unsigned short)(pv0 >> 16);
        pb[(r0 + 2) * 64 + (((gm ^ (q4 + 2)) << 3) | c7)] = (unsigned short)(pv1);
        pb[(r0 + 3) * 64 + (((gm ^ (q4 + 3)) << 3) | c7)] = (unsigned short)(pv1 >> 16);
    };
    stageV(0, 0);                              // buf0 free after pass1's final barrier
    sp_write(0, vreg[0][0], vreg[0][1]);
    __syncthreads();
    if (tid < 16) s_inv[tid] = 1.f / (s_red[tid] + s_red[16 + tid] + s_red[32 + tid] + s_red[48 + tid] + cs);
    __syncthreads();

    float inv4[4];
    #pragma unroll
    for (int r = 0; r < 4; r++) inv4[r] = s_inv[r0 + r];

    // ================= REPLAY: 1 barrier/tile; coop NT score store + PV =================
    f32x4 oacc[2];
    oacc[0] = {0.f, 0.f, 0.f, 0.f};
    oacc[1] = {0.f, 0.f, 0.f, 0.f};
    const int crow = tid >> 4, cc4 = tid & 15;             // cooperative-store coords (16 rows)
    const int cidx = crow * 64 + ((((cc4 >> 1) ^ (crow & 7)) << 3) | ((cc4 & 1) << 2));
    float* scrow = out + OUT_ELEMS + ((size_t)bh << 20) + (size_t)(n0 + crow) * 1024 + cc4 * 4;
    const float cinv = s_inv[crow];
    const int prow = l15;

    #pragma unroll
    for (int t = 0; t < 16; t++) {
        const int bb2 = t & 1;
        if (t < 15) {
            stageV(bb2 ^ 1, t + 1);
            sp_write(bb2 ^ 1, vreg[t + 1][0], vreg[t + 1][1]);
        }
        {   // cooperative coalesced score store: full 128B lines, nontemporal
            unsigned long long pk = *reinterpret_cast<const unsigned long long*>(&sPb[bb2 * 1024 + cidx]);
            f32x4 o;
            o[0] = bf2f((unsigned short)(pk      )) * cinv;
            o[1] = bf2f((unsigned short)(pk >> 16)) * cinv;
            o[2] = bf2f((unsigned short)(pk >> 32)) * cinv;
            o[3] = bf2f((unsigned short)(pk >> 48)) * cinv;
            __builtin_nontemporal_store(o, reinterpret_cast<f32x4*>(scrow + t * 64));
        }
        #pragma unroll
        for (int ks2 = 0; ks2 < 2; ks2++) {
            short8 pfr = *reinterpret_cast<const short8*>(
                &sPb[bb2 * 1024 + prow * 64 + (((ks2 * 4 + quad) ^ swz3) << 3)]);
            #pragma unroll
            for (int df = 0; df < 2; df++) {
                const int dh = wc * 32 + df * 16 + l15;
                short8 vfr = *reinterpret_cast<const short8*>(
                    &uSh[bb2 * 8192 + dh * 64 + (((ks2 * 4 + quad) ^ swz3) << 3)]);
                oacc[df] = __builtin_amdgcn_mfma_f32_16x16x32_bf16(pfr, vfr, oacc[df], 0, 0, 0);
            }
        }
        if (t < 15) __syncthreads();           // cur reads done before next overwrites
    }

    // ---- epilogue: O = inv[row] * acc (waves own disjoint (row,dh)) ----
    {
        float* obase = out + ((size_t)bh * 1024 + n0 + r0) * 128 + wc * 32 + l15;
        #pragma unroll
        for (int df = 0; df < 2; df++)
            #pragma unroll
            for (int r = 0; r < 4; r++)
                obase[(size_t)r * 128 + df * 16] = oacc[df][r] * inv4[r];
    }
}

extern "C" void kernel_launch(void* const* d_in, const int* in_sizes, int n_in,
                              void* d_out, int out_size, void* d_ws, size_t ws_size,
                              hipStream_t stream) {
    const float* q   = (const float*)d_in[0];
    const float* k   = (const float*)d_in[1];
    const float* v   = (const float*)d_in[2];
    const float* c   = (const float*)d_in[3];
    const float* dq  = (const float*)d_in[4];
    const float* dk  = (const float*)d_in[5];
    const float* w_w = (const float*)d_in[6];
    const float* b_w = (const float*)d_in[7];
    const float* w_b = (const float*)d_in[8];
    const float* b_b = (const float*)d_in[9];
    float* out = (float*)d_out;
    char* ws = (char*)d_ws;
    unsigned short* wsK  = (unsigned short*)(ws + WS_K);
    unsigned short* wsVt = (unsigned short*)(ws + WS_VT);
    float* wsCs   = (float*)(ws + WS_CS);

    hipLaunchKernelGGL(prep_all, dim3(1056), dim3(256), 0, stream, k, v, c, wsK, wsVt, wsCs);
    hipLaunchKernelGGL(sam_main, dim3(2048), dim3(256), 0, stream,
                       q, dq, dk, w_w, b_w, w_b, b_b, wsK, wsVt, wsCs, out);
}

// Round 10
// 254.802 us; speedup vs baseline: 1.1330x; 1.0478x over previous
//
#include <hip/hip_runtime.h>

// RelativeSAMAttention: B=4,H=8,N=1024,DH=128. Outputs FP32: out[B,H,N,DH] ++ scores[B,H,N,N].
//
// R13: R8 (88.4us verified best) + T4 counted-vmcnt pipelining (guide m218: counted vs
// drain-0 = +38-73%). R8 drains vmcnt(0) at all 31 loop barriers, killing its own
// distance-1 prefetch. Here: 3-buffer staging (48KB region, K-phase then V-phase),
// prefetch distance 2, barriers = "s_waitcnt vmcnt(N) lgkmcnt(0); s_barrier" with
// exact N (pass1: 2 = stageK(t+2) in flight; replay: 3 = NT(t)+stageV(t+2)).
// To make N exact, per-tile dk loads move to a prologue-staged LDS table {x,y,z,sq}
// (no stray vmem in the loops). NT score store first in replay iter. Tails drain
// (t=14: vmcnt(0)/(1)); full __syncthreads only at phase boundaries.
// Verified-R8 loop bodies otherwise byte-identical; launch_bounds(512,4) (spill lesson);
// LDS ~74KB -> 2 blocks/CU.

typedef __attribute__((ext_vector_type(8))) short short8;
typedef __attribute__((ext_vector_type(4))) float f32x4;

#define OUT_ELEMS 4194304ull
#define WS_K      0ull           //  8388608 B bf16 K [bh][m][dh]
#define WS_VT     8388608ull     //  8388608 B bf16 V^T [bh][dh][m]
#define WS_CS     16777216ull    //      128 B fp32 cs[32]

// counted barrier: leave N newest vmem ops in flight; drain everything older + all LDS
#define CBAR(N) asm volatile("s_waitcnt vmcnt(" #N ") lgkmcnt(0)\n\ts_barrier" ::: "memory")
#define LBAR()  asm volatile("s_waitcnt lgkmcnt(0)\n\ts_barrier" ::: "memory")

__device__ __forceinline__ unsigned short f2bf(float f) {
    unsigned u = __builtin_bit_cast(unsigned, f);
    u += 0x7FFFu + ((u >> 16) & 1u);
    return (unsigned short)(u >> 16);
}
__device__ __forceinline__ float bf2f(unsigned short u) {
    return __builtin_bit_cast(float, (unsigned)u << 16);
}
__device__ __forceinline__ float softplus(float x) {
    return fmaxf(x, 0.f) + __logf(1.f + __expf(-fabsf(x)));
}
__device__ __forceinline__ unsigned cvt_pk_bf16(float lo, float hi) {
    unsigned r;
    asm("v_cvt_pk_bf16_f32 %0, %1, %2" : "=v"(r) : "v"(lo), "v"(hi));
    return r;
}
__device__ __forceinline__ void gl_lds16(const unsigned short* g, unsigned short* l) {
    __builtin_amdgcn_global_load_lds(
        (const __attribute__((address_space(1))) void*)g,
        (__attribute__((address_space(3))) void*)l, 16, 0, 0);
}

// ---------------- merged prep: blocks [0,512) K-convert, [512,1024) V-transpose, [1024,1056) cs ----
__global__ __launch_bounds__(256) void prep_all(
    const float* __restrict__ k, const float* __restrict__ v, const float* __restrict__ c,
    unsigned short* __restrict__ wsK, unsigned short* __restrict__ wsVt, float* __restrict__ wsCs)
{
    __shared__ unsigned short sT[64 * 132];
    const int blk = blockIdx.x, tid = threadIdx.x;
    if (blk < 512) {
        int t = blk * 256 + tid;
        for (int u = t; u < 524288; u += 131072) {
            float4 a = reinterpret_cast<const float4*>(k)[u * 2];
            float4 b = reinterpret_cast<const float4*>(k)[u * 2 + 1];
            short8 o;
            o[0]=(short)f2bf(a.x); o[1]=(short)f2bf(a.y); o[2]=(short)f2bf(a.z); o[3]=(short)f2bf(a.w);
            o[4]=(short)f2bf(b.x); o[5]=(short)f2bf(b.y); o[6]=(short)f2bf(b.z); o[7]=(short)f2bf(b.w);
            reinterpret_cast<short8*>(wsK)[u] = o;
        }
    } else if (blk < 1024) {
        const int vb = blk - 512;
        const int bh = vb >> 4, m0 = (vb & 15) * 64;
        const float* src = v + ((size_t)bh * 1024 + m0) * 128;
        for (int i = tid; i < 2048; i += 256) {
            int row = i >> 5, c4 = i & 31;
            float4 t = reinterpret_cast<const float4*>(src)[i];
            unsigned long long pk = (unsigned long long)f2bf(t.x)
                                  | ((unsigned long long)f2bf(t.y) << 16)
                                  | ((unsigned long long)f2bf(t.z) << 32)
                                  | ((unsigned long long)f2bf(t.w) << 48);
            *reinterpret_cast<unsigned long long*>(&sT[row * 132 + c4 * 4]) = pk;
        }
        __syncthreads();
        for (int u = tid; u < 2048; u += 256) {
            int dh = u >> 4, ms = u & 15;
            unsigned long long pk = (unsigned long long)sT[(ms*4+0)*132 + dh]
                                  | ((unsigned long long)sT[(ms*4+1)*132 + dh] << 16)
                                  | ((unsigned long long)sT[(ms*4+2)*132 + dh] << 32)
                                  | ((unsigned long long)sT[(ms*4+3)*132 + dh] << 48);
            *reinterpret_cast<unsigned long long*>(&wsVt[((size_t)bh * 128 + dh) * 1024 + m0 + ms * 4]) = pk;
        }
    } else {
        __shared__ float red[4];
        const int bh = blk - 1024;
        float p = 0.f;
        for (int i = tid; i < 1024; i += 256) p += softplus(c[(size_t)bh * 1024 + i]);
        p += __shfl_xor(p, 32, 64); p += __shfl_xor(p, 16, 64); p += __shfl_xor(p, 8, 64);
        p += __shfl_xor(p,  4, 64); p += __shfl_xor(p,  2, 64); p += __shfl_xor(p, 1, 64);
        if ((tid & 63) == 0) red[tid >> 6] = p;
        __syncthreads();
        if (tid == 0) wsCs[bh] = red[0] + red[1] + red[2] + red[3] + 1e-9f;
    }
}

// ---------------- main: distance-2 prefetch, counted-vmcnt barriers ----------------
__global__ __launch_bounds__(512, 4) void sam_main(
    const float* __restrict__ q, const float* __restrict__ dqp, const float* __restrict__ dkp,
    const float* __restrict__ w_w, const float* __restrict__ b_w,
    const float* __restrict__ w_b, const float* __restrict__ b_b,
    const unsigned short* __restrict__ wsK, const unsigned short* __restrict__ wsVt,
    const float* __restrict__ wsCs, float* __restrict__ out)
{
    __shared__ __align__(16) unsigned short uSh[24576];  // 48KB: 3 bufs x 8192 shorts (K tiles / V tiles); sQ in buf0
    __shared__ __align__(16) float sdkf[4096];           // 16KB: dk table [m]{x,y,z,sq}
    __shared__ __align__(16) unsigned short sPb[4096];   //  8KB: sP[2][32][64], granule-XOR swizzled
    __shared__ float s_red[128];
    __shared__ float s_inv[32];

    const int bid  = blockIdx.x;
    const int xcd  = bid & 7;                 // round-robin XCD assumption (perf-only)
    const int j    = bid >> 3;                // 0..127 within XCD
    const int bh   = xcd * 4 + (j >> 5);      // bh-MAJOR: concurrent blocks share one bh (512KB, L2-hot)
    const int n0   = (j & 31) * 32;
    const int b    = bh >> 3;
    const int h    = bh & 7;
    const int tid  = threadIdx.x;
    const int lane = tid & 63;
    const int wave = tid >> 6;
    const int l15  = lane & 15;
    const int quad = lane >> 4;
    const int wr   = wave >> 2;               // row half (16 rows)
    const int wc   = wave & 3;                // col quarter (16 m) / dh quarter (32 dh)
    const int mq   = wc * 16 + l15;
    const int swz3 = l15 & 7;
    const int r0   = wr * 16 + quad * 4;
    const int q4   = (quad & 1) * 4;          // (r0+r)&7 = q4+r (no carry, r<4)

    const float ww = w_w[h], bw = b_w[h], wb = w_b[h], bb = b_b[h];
    const float wwn = -ww, bwn = -bw;
    const float SCALE = 0.08838834764831845f;   // 1/sqrt(128), folded into Q

    // ---- staging geometry ----
    const unsigned short* gKbh = wsK  + (size_t)bh * 131072;
    const unsigned short* gVbh = wsVt + (size_t)bh * 131072;
    const int krow  = tid >> 4;                                 // K-stage row (i=0): 0..31
    const int koff0 = krow * 128 + (((tid & 15) ^ (krow & 7)) << 3);
    const int vdh   = tid >> 3;                                 // V-stage dh (i=0): 0..63
    const int voff0 = vdh * 1024 + (((tid & 7) ^ (vdh & 7)) << 3);
    const int ldsoW = wave * 512;                               // wave-uniform dest (shorts)

    auto stageK = [&](int buf, int t) {                         // K tile t -> buf (0..2)
        const unsigned short* g = gKbh + t * 8192 + koff0;
        gl_lds16(g,        &uSh[buf * 8192 + ldsoW]);
        gl_lds16(g + 4096, &uSh[buf * 8192 + 4096 + ldsoW]);    // row+32: same low3 bits
    };
    auto stageV = [&](int buf, int t) {                         // V tile t -> buf (0..2)
        const unsigned short* g = gVbh + t * 64 + voff0;
        gl_lds16(g,         &uSh[buf * 8192 + ldsoW]);
        gl_lds16(g + 65536, &uSh[buf * 8192 + 4096 + ldsoW]);   // dh+64: same low3 bits
    };

    // ---- prologue: Q rows -> bf16 (pre-scaled) sQ (buf0); dk -> LDS table; dq geometry ----
    {
        const float* qbase = q + ((size_t)bh * 1024 + n0) * 128;
        for (int i = tid; i < 1024; i += 512) {
            int row = i >> 5, c4 = i & 31;
            float4 t = reinterpret_cast<const float4*>(qbase)[i];
            unsigned long long pk = (unsigned long long)f2bf(t.x * SCALE)
                                  | ((unsigned long long)f2bf(t.y * SCALE) << 16)
                                  | ((unsigned long long)f2bf(t.z * SCALE) << 32)
                                  | ((unsigned long long)f2bf(t.w * SCALE) << 48);
            *reinterpret_cast<unsigned long long*>(&uSh[row * 136 + c4 * 4]) = pk;
        }
        #pragma unroll
        for (int i = 0; i < 2; i++) {                          // dk table: m = tid, tid+512
            int m = tid + i * 512;
            float4 d4 = reinterpret_cast<const float4*>(dkp)[(size_t)b * 1024 + m];
            f32x4 e;
            e[0] = d4.x; e[1] = d4.y; e[2] = d4.z;
            e[3] = d4.x*d4.x + d4.y*d4.y + d4.z*d4.z;
            *reinterpret_cast<f32x4*>(&sdkf[m * 4]) = e;
        }
    }
    float qxm[4], qym[4], qzm[4], qs[4];
    #pragma unroll
    for (int r = 0; r < 4; r++) {
        float4 d4 = reinterpret_cast<const float4*>(dqp)[(size_t)b * 1024 + n0 + r0 + r];
        qxm[r] = -2.f * d4.x; qym[r] = -2.f * d4.y; qzm[r] = -2.f * d4.z;
        qs[r] = d4.x*d4.x + d4.y*d4.y + d4.z*d4.z;
    }
    const float cs = wsCs[bh];
    __syncthreads();                           // sQ + sdkf visible
    short8 afr[4];
    {
        const unsigned short* aq = &uSh[(wr * 16 + l15) * 136 + quad * 8];
        #pragma unroll
        for (int ks = 0; ks < 4; ks++)
            afr[ks] = *reinterpret_cast<const short8*>(aq + ks * 32);
    }
    __syncthreads();                           // all afr reads done; buf0 free for K0
    stageK(0, 0);
    stageK(1, 1);
    CBAR(2);                                   // K0 landed; K1 stays in flight

    // ================= PASS 1: distance-2 prefetch, counted barriers =================
    float rs[4] = {0.f, 0.f, 0.f, 0.f};
    unsigned vreg[16][2];                      // raw-score cache: 16 tiles x 4 vals packed bf16
    #pragma unroll
    for (int t = 0; t < 16; t++) {
        if (t < 14) stageK((t + 2) % 3, t + 2);     // in flight across next barrier
        f32x4 cacc = {0.f, 0.f, 0.f, 0.f};
        const unsigned short* bq = &uSh[(t % 3) * 8192 + mq * 128];
        #pragma unroll
        for (int ks = 0; ks < 4; ks++) {
            short8 bfr = *reinterpret_cast<const short8*>(bq + (((ks * 4 + quad) ^ swz3) << 3));
            cacc = __builtin_amdgcn_mfma_f32_16x16x32_bf16(afr[ks], bfr, cacc, 0, 0, 0);
        }
        f32x4 dk4 = *reinterpret_cast<const f32x4*>(&sdkf[(t * 64 + mq) * 4]);
        float val[4];
        #pragma unroll
        for (int r = 0; r < 4; r++) {
            float dist = qs[r] + dk4[3] + qxm[r]*dk4[0] + qym[r]*dk4[1] + qzm[r]*dk4[2];
            float aw = softplus(dist * wwn + bwn);
            float ab = dist * wb + bb;
            val[r] = fmaxf(cacc[r] * aw + ab, 0.f);
            rs[r] += val[r];
        }
        vreg[t][0] = cvt_pk_bf16(val[0], val[1]);
        vreg[t][1] = cvt_pk_bf16(val[2], val[3]);
        if (t < 14)      CBAR(2);              // drain K(t+1), leave K(t+2)
        else if (t == 14) CBAR(0);             // drain K15 for final tile
        else              __syncthreads();     // phase boundary: full drain, buffers free
    }

    // ---- transition: rowsums -> invd; V pipeline warm-up ----
    #pragma unroll
    for (int r = 0; r < 4; r++) {
        float ts = rs[r];
        ts += __shfl_xor(ts, 1, 64);
        ts += __shfl_xor(ts, 2, 64);
        ts += __shfl_xor(ts, 4, 64);
        ts += __shfl_xor(ts, 8, 64);
        if (l15 == 0) s_red[wc * 32 + r0 + r] = ts;
    }
    auto sp_write = [&](int buf, unsigned pv0, unsigned pv1) {
        unsigned short* pb = sPb + buf * 2048;
        const int gm = mq >> 3, c7 = mq & 7;
        pb[(r0 + 0) * 64 + (((gm ^ (q4 + 0)) << 3) | c7)] = (unsigned short)(pv0);
        pb[(r0 + 1) * 64 + (((gm ^ (q4 + 1)) << 3) | c7)] = (unsigned short)(pv0 >> 16);
        pb[(r0 + 2) * 64 + (((gm ^ (q4 + 2)) << 3) | c7)] = (unsigned short)(pv1);
        pb[(r0 + 3) * 64 + (((gm ^ (q4 + 3)) << 3) | c7)] = (unsigned short)(pv1 >> 16);
    };
    stageV(0, 0);
    stageV(1, 1);
    sp_write(0, vreg[0][0], vreg[0][1]);
    CBAR(2);                                   // V0 landed + s_red/sP visible; V1 in flight
    if (tid < 32) s_inv[tid] = 1.f / (s_red[tid] + s_red[32 + tid] + s_red[64 + tid] + s_red[96 + tid] + cs);
    LBAR();                                    // s_inv visible; V1 stays in flight

    float inv4[4];
    #pragma unroll
    for (int r = 0; r < 4; r++) inv4[r] = s_inv[r0 + r];

    // ================= REPLAY: distance-2 V prefetch; NT stores never force-drained =================
    f32x4 oacc[2];
    oacc[0] = {0.f, 0.f, 0.f, 0.f};
    oacc[1] = {0.f, 0.f, 0.f, 0.f};
    const int crow = tid >> 4, cc4 = tid & 15;             // cooperative-store coords
    const int cidx = crow * 64 + ((((cc4 >> 1) ^ (crow & 7)) << 3) | ((cc4 & 1) << 2));
    float* scrow = out + OUT_ELEMS + ((size_t)bh << 20) + (size_t)(n0 + crow) * 1024 + cc4 * 4;
    const float cinv = s_inv[crow];
    const int prow = wr * 16 + l15;

    #pragma unroll
    for (int t = 0; t < 16; t++) {
        const int bb2 = t & 1;
        {   // NT score store FIRST (its ack rides in the counted window)
            unsigned long long pk = *reinterpret_cast<const unsigned long long*>(&sPb[bb2 * 2048 + cidx]);
            f32x4 o;
            o[0] = bf2f((unsigned short)(pk      )) * cinv;
            o[1] = bf2f((unsigned short)(pk >> 16)) * cinv;
            o[2] = bf2f((unsigned short)(pk >> 32)) * cinv;
            o[3] = bf2f((unsigned short)(pk >> 48)) * cinv;
            __builtin_nontemporal_store(o, reinterpret_cast<f32x4*>(scrow + t * 64));
        }
        if (t < 14) stageV((t + 2) % 3, t + 2);
        if (t < 15) sp_write(bb2 ^ 1, vreg[t + 1][0], vreg[t + 1][1]);
        #pragma unroll
        for (int ks2 = 0; ks2 < 2; ks2++) {
            short8 pfr = *reinterpret_cast<const short8*>(
                &sPb[bb2 * 2048 + prow * 64 + (((ks2 * 4 + quad) ^ swz3) << 3)]);
            #pragma unroll
            for (int df = 0; df < 2; df++) {
                const int dh = wc * 32 + df * 16 + l15;
                short8 vfr = *reinterpret_cast<const short8*>(
                    &uSh[(t % 3) * 8192 + dh * 64 + (((ks2 * 4 + quad) ^ swz3) << 3)]);
                oacc[df] = __builtin_amdgcn_mfma_f32_16x16x32_bf16(pfr, vfr, oacc[df], 0, 0, 0);
            }
        }
        if (t < 14)      CBAR(3);              // drain {NT(t-1), V(t+1)}; leave {NT(t), V(t+2)}
        else if (t == 14) CBAR(1);             // drain V15 for final tile; leave NT(14)
        // t == 15: no barrier
    }

    // ---- epilogue: O = inv[row] * acc (waves own disjoint (row,dh)) ----
    {
        float* obase = out + ((size_t)bh * 1024 + n0 + r0) * 128 + wc * 32 + l15;
        #pragma unroll
        for (int df = 0; df < 2; df++)
            #pragma unroll
            for (int r = 0; r < 4; r++)
                obase[(size_t)r * 128 + df * 16] = oacc[df][r] * inv4[r];
    }
}

extern "C" void kernel_launch(void* const* d_in, const int* in_sizes, int n_in,
                              void* d_out, int out_size, void* d_ws, size_t ws_size,
                              hipStream_t stream) {
    const float* q   = (const float*)d_in[0];
    const float* k   = (const float*)d_in[1];
    const float* v   = (const float*)d_in[2];
    const float* c   = (const float*)d_in[3];
    const float* dq  = (const float*)d_in[4];
    const float* dk  = (const float*)d_in[5];
    const float* w_w = (const float*)d_in[6];
    const float* b_w = (const float*)d_in[7];
    const float* w_b = (const float*)d_in[8];
    const float* b_b = (const float*)d_in[9];
    float* out = (float*)d_out;
    char* ws = (char*)d_ws;
    unsigned short* wsK  = (unsigned short*)(ws + WS_K);
    unsigned short* wsVt = (unsigned short*)(ws + WS_VT);
    float* wsCs   = (float*)(ws + WS_CS);

    hipLaunchKernelGGL(prep_all, dim3(1056), dim3(256), 0, stream, k, v, c, wsK, wsVt, wsCs);
    hipLaunchKernelGGL(sam_main, dim3(1024), dim3(512), 0, stream,
                       q, dq, dk, w_w, b_w, w_b, b_b, wsK, wsVt, wsCs, out);
}